// Round 4
// baseline (880.933 us; speedup 1.0000x reference)
//
#include <hip/hip_runtime.h>
#include <cstdint>
#include <cstddef>

// Problem constants
#define NB    4
#define SEQ   4096
#define EDIM  1024
#define DHEAD 512
#define NTOK  (NB * SEQ)     // 16384
#define FQK   2048           // Q and K features only
#define FQKV  2560

typedef __bf16 bf16x8 __attribute__((ext_vector_type(8)));
typedef float  f32x4  __attribute__((ext_vector_type(4)));

__device__ __forceinline__ unsigned short f2bf(float f) {
  union { float f; unsigned int u; } v; v.f = f;
  return (unsigned short)((v.u + 0x7fffu + ((v.u >> 16) & 1u)) >> 16);
}
__device__ __forceinline__ float bf2f(unsigned short h) {
  union { unsigned int u; float f; } v; v.u = ((unsigned int)h) << 16;
  return v.f;
}

// async global->LDS, 16B per lane; LDS dest wave-uniform base, lane i -> base+i*16.
__device__ __forceinline__ void gld_lds16(const void* g, void* l) {
  __builtin_amdgcn_global_load_lds(
      (const __attribute__((address_space(1))) unsigned int*)g,
      (__attribute__((address_space(3))) unsigned int*)l, 16, 0, 0);
}

// ---------------------------------------------------------------------------
// m97-style GEMM-BT core: C(128x128) = A(128xK) * B(128xK)^T, bf16 in, fp32 acc.
// A rows m0..m0+127 (lda), B rows n0..n0+127 (ldb). 256 thr = 4 waves 2x2.
// epi(acc, wr, wc, lane): C[m][n], m = m0+wr*64+tm*16+(lane>>4)*4+i,
// n = n0+wc*64+tn*16+(lane&15).
// ---------------------------------------------------------------------------
template <class Epi>
__device__ __forceinline__ void gemm_bt_core(
    const unsigned short* __restrict__ A, const unsigned short* __restrict__ B,
    int K, int lda, int ldb, int m0, int n0, Epi epi) {
  __shared__ __align__(16) unsigned short As[128 * 32];
  __shared__ __align__(16) unsigned short Bs[128 * 32];
  const int t = threadIdx.x;
  const int w = t >> 6;
  const int lane = t & 63;
  const int wr = w >> 1, wc = w & 1;

  f32x4 acc[4][4];
#pragma unroll
  for (int i = 0; i < 4; ++i)
#pragma unroll
    for (int j = 0; j < 4; ++j) acc[i][j] = f32x4{0.f, 0.f, 0.f, 0.f};

  const int c0 = (w * 2) * 64 + lane;
  const int c1 = (w * 2 + 1) * 64 + lane;
  const int r0 = c0 >> 2, col0 = (c0 & 3) * 8;
  const int r1 = c1 >> 2, col1 = (c1 & 3) * 8;
  unsigned short* ldsA0 = &As[(w * 2) * 512];       // wave-uniform
  unsigned short* ldsA1 = &As[(w * 2 + 1) * 512];
  unsigned short* ldsB0 = &Bs[(w * 2) * 512];
  unsigned short* ldsB1 = &Bs[(w * 2 + 1) * 512];
  const unsigned short* gA0 = A + (size_t)(m0 + r0) * lda + col0;
  const unsigned short* gA1 = A + (size_t)(m0 + r1) * lda + col1;
  const unsigned short* gB0 = B + (size_t)(n0 + r0) * ldb + col0;
  const unsigned short* gB1 = B + (size_t)(n0 + r1) * ldb + col1;

  for (int kt = 0; kt < K; kt += 32) {
    gld_lds16(gA0 + kt, ldsA0);
    gld_lds16(gA1 + kt, ldsA1);
    gld_lds16(gB0 + kt, ldsB0);
    gld_lds16(gB1 + kt, ldsB1);
    __syncthreads();

    bf16x8 af[4], bfr[4];
#pragma unroll
    for (int tm = 0; tm < 4; ++tm) {
      int r = wr * 64 + tm * 16 + (lane & 15);
      af[tm] = *(const bf16x8*)&As[r * 32 + (lane >> 4) * 8];
    }
#pragma unroll
    for (int tn = 0; tn < 4; ++tn) {
      int r = wc * 64 + tn * 16 + (lane & 15);
      bfr[tn] = *(const bf16x8*)&Bs[r * 32 + (lane >> 4) * 8];
    }
#pragma unroll
    for (int tm = 0; tm < 4; ++tm)
#pragma unroll
      for (int tn = 0; tn < 4; ++tn)
        acc[tm][tn] = __builtin_amdgcn_mfma_f32_16x16x32_bf16(
            af[tm], bfr[tn], acc[tm][tn], 0, 0, 0);
    __syncthreads();
  }
  epi(acc, wr, wc, lane);
}

// ---------------------------------------------------------------------------
// Utility kernels
// ---------------------------------------------------------------------------
__global__ void k_cvt_x(const float* __restrict__ X, unsigned short* __restrict__ Xb) {
  int i = blockIdx.x * blockDim.x + threadIdx.x;
  float4 v = ((const float4*)X)[i];
  ushort4 o;
  o.x = f2bf(v.x); o.y = f2bf(v.y); o.z = f2bf(v.z); o.w = f2bf(v.w);
  ((ushort4*)Xb)[i] = o;
}

__global__ void k_pack_w(const float* __restrict__ Wq, const float* __restrict__ Wk,
                         const float* __restrict__ Wv, unsigned short* __restrict__ Wb) {
  int i = blockIdx.x * blockDim.x + threadIdx.x;
  int idx = i * 4;
  int f = idx >> 10, e = idx & 1023;
  const float* src = (f < 1024) ? (Wq + (size_t)f * 1024)
                   : (f < 2048) ? (Wk + (size_t)(f - 1024) * 1024)
                                : (Wv + (size_t)(f - 2048) * 1024);
  float4 v = *(const float4*)(src + e);
  ushort4 o;
  o.x = f2bf(v.x); o.y = f2bf(v.y); o.z = f2bf(v.z); o.w = f2bf(v.w);
  ((ushort4*)Wb)[i] = o;
}

__global__ void k_pack_b(const float* __restrict__ bq, const float* __restrict__ bk,
                         const float* __restrict__ bv, float* __restrict__ bc) {
  int f = blockIdx.x * blockDim.x + threadIdx.x;
  if (f < FQKV)
    bc[f] = (f < 1024) ? bq[f] : (f < 2048) ? bk[f - 1024] : bv[f - 2048];
}

__global__ void k_zero_f(float* __restrict__ p) {
  int i = blockIdx.x * blockDim.x + threadIdx.x;
  p[i] = 0.f;
}

// ---------------------------------------------------------------------------
// GEMM kernels
// ---------------------------------------------------------------------------
// QK[n][f] = sum_e Xb[n][e]*Wb[f][e] + bc[f], f in [0,2048)   (bf16 out)
// Epilogue: C-tile -> padded LDS -> coalesced dwordx4 stores.
__global__ __launch_bounds__(256) void k_qk(const unsigned short* __restrict__ Xb,
                                            const unsigned short* __restrict__ Wb,
                                            const float* __restrict__ bc,
                                            unsigned short* __restrict__ QK) {
  __shared__ __align__(16) unsigned short Ps[128 * 136];  // pad 8 -> 272B pitch
  const int m0 = blockIdx.y * 128, n0 = blockIdx.x * 128;
  gemm_bt_core(Xb, Wb, EDIM, EDIM, EDIM, m0, n0,
    [&](f32x4 (&acc)[4][4], int wr, int wc, int lane) {
      const int w = wr * 2 + wc;
#pragma unroll
      for (int tm = 0; tm < 4; ++tm)
#pragma unroll
        for (int tn = 0; tn < 4; ++tn) {
          int kc = wc * 64 + tn * 16 + (lane & 15);
          float bias = bc[n0 + kc];
#pragma unroll
          for (int i = 0; i < 4; ++i) {
            int ql = wr * 64 + tm * 16 + (lane >> 4) * 4 + i;
            Ps[ql * 136 + kc] = f2bf(acc[tm][tn][i] + bias);
          }
        }
      __syncthreads();
#pragma unroll
      for (int j = 0; j < 8; ++j) {
        int row = w * 32 + j * 4 + (lane >> 4);
        int col = (lane & 15) * 8;
        uint4 v = *(const uint4*)&Ps[row * 136 + col];
        *(uint4*)&QK[(size_t)(m0 + row) * FQK + n0 + col] = v;
      }
    });
}

// Vt[b][d][s] = sum_e Wv[d][e]*Xb[b*SEQ+s][e] + bv[d]   (bf16, transposed V)
__global__ __launch_bounds__(256) void k_v(const unsigned short* __restrict__ Xb,
                                           const unsigned short* __restrict__ Wb,
                                           const float* __restrict__ bc,
                                           unsigned short* __restrict__ Vt) {
  const int b = blockIdx.z;
  const int m0 = blockIdx.y * 128;  // d tile
  const int n0 = blockIdx.x * 128;  // s tile
  const unsigned short* A = Wb + (size_t)2048 * EDIM;
  const unsigned short* B = Xb + (size_t)b * SEQ * EDIM;
  unsigned short* Vb = Vt + (size_t)b * DHEAD * SEQ;
  gemm_bt_core(A, B, EDIM, EDIM, EDIM, m0, n0,
    [&](f32x4 (&acc)[4][4], int wr, int wc, int lane) {
#pragma unroll
      for (int tm = 0; tm < 4; ++tm)
#pragma unroll
        for (int tn = 0; tn < 4; ++tn) {
          int s = n0 + wc * 64 + tn * 16 + (lane & 15);
#pragma unroll
          for (int i = 0; i < 4; ++i) {
            int d = m0 + wr * 64 + tm * 16 + (lane >> 4) * 4 + i;
            Vb[(size_t)d * SEQ + s] = f2bf(acc[tm][tn][i] + bc[2048 + d]);
          }
        }
    });
}

// Chunk of 2 batches, both which: z = blockIdx.z -> (rb=z>>1, which=z&1).
// E_c[z][q][k] = exp(s*Q.K); row sums atomically into ls[which][b][q].
// Epilogue: P-tile -> padded LDS -> coalesced dwordx4 stores.
__global__ __launch_bounds__(256) void k_scores2(const unsigned short* __restrict__ QK,
                                                 unsigned short* __restrict__ E_c,
                                                 float* __restrict__ ls, int b0) {
  __shared__ __align__(16) unsigned short Ps[128 * 136];
  const int z = blockIdx.z;
  const int rb = z >> 1, which = z & 1;
  const int b = b0 + rb;
  const int m0 = blockIdx.y * 128;  // q tile
  const int n0 = blockIdx.x * 128;  // k tile
  const unsigned short* Aq = QK + (size_t)b * SEQ * FQK + which * 512;
  const unsigned short* Bk = QK + (size_t)b * SEQ * FQK + 1024 + which * 512;
  unsigned short* Eb = E_c + (size_t)z * SEQ * SEQ;
  float* lr = ls + (size_t)which * NTOK + (size_t)b * SEQ;
  gemm_bt_core(Aq, Bk, 512, FQK, FQK, m0, n0,
    [&](f32x4 (&acc)[4][4], int wr, int wc, int lane) {
      const float scale = 0.04419417382415922f;  // 1/sqrt(512)
      const int w = wr * 2 + wc;
      float rs[4][4];
#pragma unroll
      for (int tm = 0; tm < 4; ++tm)
#pragma unroll
        for (int i = 0; i < 4; ++i) rs[tm][i] = 0.f;
#pragma unroll
      for (int tm = 0; tm < 4; ++tm)
#pragma unroll
        for (int tn = 0; tn < 4; ++tn) {
          int kc = wc * 64 + tn * 16 + (lane & 15);
#pragma unroll
          for (int i = 0; i < 4; ++i) {
            int ql = wr * 64 + tm * 16 + (lane >> 4) * 4 + i;
            float e = __expf(acc[tm][tn][i] * scale);
            unsigned short eb = f2bf(e);
            Ps[ql * 136 + kc] = eb;
            rs[tm][i] += bf2f(eb);  // sum the rounded value for consistency
          }
        }
#pragma unroll
      for (int tm = 0; tm < 4; ++tm)
#pragma unroll
        for (int i = 0; i < 4; ++i) {
          float v = rs[tm][i];
          v += __shfl_xor(v, 1);
          v += __shfl_xor(v, 2);
          v += __shfl_xor(v, 4);
          v += __shfl_xor(v, 8);
          rs[tm][i] = v;
        }
      if ((lane & 15) == 0) {
#pragma unroll
        for (int tm = 0; tm < 4; ++tm)
#pragma unroll
          for (int i = 0; i < 4; ++i) {
            int q = m0 + wr * 64 + tm * 16 + (lane >> 4) * 4 + i;
            atomicAdd(&lr[q], rs[tm][i]);
          }
      }
      __syncthreads();
#pragma unroll
      for (int j = 0; j < 8; ++j) {
        int row = w * 32 + j * 4 + (lane >> 4);
        int col = (lane & 15) * 8;
        uint4 v = *(const uint4*)&Ps[row * 136 + col];
        *(uint4*)&Eb[(size_t)(m0 + row) * SEQ + n0 + col] = v;
      }
    });
}

// O12[z][q][d] = sum_k E_c[z][q][k] * Vt[b][d][k]  (fp32, un-normalized).
// Read-E-once tiling: block = 32 q-rows x full 512 d, K = 4096.
// grid (SEQ/32, 4). 4 waves; wave w owns d-range [w*128, w*128+128).
__global__ __launch_bounds__(256) void k_pv3(const unsigned short* __restrict__ E_c,
                                             const unsigned short* __restrict__ Vt,
                                             float* __restrict__ O12, int b0) {
  __shared__ __align__(16) unsigned short As[32 * 32];    // E strip chunk, 2 KB
  __shared__ __align__(16) unsigned short Bs[512 * 32];   // Vt chunk, 32 KB
  const int z = blockIdx.y;
  const int b = b0 + (z >> 1);
  const int m0 = blockIdx.x * 32;
  const unsigned short* A = E_c + (size_t)z * SEQ * SEQ;   // rows m0..m0+31, lda SEQ
  const unsigned short* Bv = Vt + (size_t)b * DHEAD * SEQ; // rows 0..511,  ldb SEQ
  float* Ob = O12 + (size_t)z * SEQ * DHEAD;
  const int t = threadIdx.x, w = t >> 6, lane = t & 63;

  f32x4 acc[2][8];
#pragma unroll
  for (int i = 0; i < 2; ++i)
#pragma unroll
    for (int j = 0; j < 8; ++j) acc[i][j] = f32x4{0.f, 0.f, 0.f, 0.f};

  // B staging: 512x32 = 2048 16B-chunks; wave w stages chunks [w*512, w*512+512)
  // via 8 glds. chunk c: row=c>>2, col=(c&3)*8.
  const int bcw = w * 512;
  const unsigned short* gB[8];
#pragma unroll
  for (int g = 0; g < 8; ++g) {
    int c = bcw + g * 64 + lane;
    gB[g] = Bv + (size_t)(c >> 2) * SEQ + (c & 3) * 8;
  }
  // A staging: 32x32 = 128 chunks; wave 0 stages via 2 glds.
  const int ca0 = lane, ca1 = 64 + lane;
  const unsigned short* gA0 = A + (size_t)(m0 + (ca0 >> 2)) * SEQ + (ca0 & 3) * 8;
  const unsigned short* gA1 = A + (size_t)(m0 + (ca1 >> 2)) * SEQ + (ca1 & 3) * 8;

  for (int kt = 0; kt < SEQ; kt += 32) {
    if (w == 0) {
      gld_lds16(gA0 + kt, As);
      gld_lds16(gA1 + kt, As + 512);
    }
#pragma unroll
    for (int g = 0; g < 8; ++g)
      gld_lds16(gB[g] + kt, Bs + (bcw + g * 64) * 8);
    __syncthreads();

    bf16x8 af[2], bfr[8];
#pragma unroll
    for (int tm = 0; tm < 2; ++tm)
      af[tm] = *(const bf16x8*)&As[(tm * 16 + (lane & 15)) * 32 + (lane >> 4) * 8];
#pragma unroll
    for (int tn = 0; tn < 8; ++tn) {
      int r = w * 128 + tn * 16 + (lane & 15);
      bfr[tn] = *(const bf16x8*)&Bs[r * 32 + (lane >> 4) * 8];
    }
#pragma unroll
    for (int tm = 0; tm < 2; ++tm)
#pragma unroll
      for (int tn = 0; tn < 8; ++tn)
        acc[tm][tn] = __builtin_amdgcn_mfma_f32_16x16x32_bf16(
            af[tm], bfr[tn], acc[tm][tn], 0, 0, 0);
    __syncthreads();
  }

#pragma unroll
  for (int tm = 0; tm < 2; ++tm)
#pragma unroll
    for (int tn = 0; tn < 8; ++tn) {
      int d = w * 128 + tn * 16 + (lane & 15);
#pragma unroll
      for (int i = 0; i < 4; ++i) {
        int q = m0 + tm * 16 + (lane >> 4) * 4 + i;
        Ob[(size_t)q * DHEAD + d] = acc[tm][tn][i];
      }
    }
}

// Chunk combine: out[b0+rb] = O12[rb*2+0]/l1 - lambda * O12[rb*2+1]/l2
__global__ void k_combine(const float* __restrict__ O12, const float* __restrict__ ls,
                          const float* __restrict__ lam, float* __restrict__ out, int b0) {
  int i = blockIdx.x * blockDim.x + threadIdx.x;
  float lambda = expf(lam[0]) + 0.05f;
  int gq = i >> 7;
  int rb = gq >> 12;
  int q = gq & 4095;
  int dv = i & 127;
  int b = b0 + rb;
  float inv1 = 1.f / ls[(size_t)b * SEQ + q];
  float inv2 = lambda / ls[NTOK + (size_t)b * SEQ + q];
  size_t ai = (size_t)(rb * 2) * (SEQ * 128) + (size_t)q * 128 + dv;
  float4 a = ((const float4*)O12)[ai];
  float4 c = ((const float4*)O12)[ai + SEQ * 128];
  float4 r;
  r.x = a.x * inv1 - c.x * inv2;
  r.y = a.y * inv1 - c.y * inv2;
  r.z = a.z * inv1 - c.z * inv2;
  r.w = a.w * inv1 - c.w * inv2;
  ((float4*)out)[(size_t)(b * SEQ + q) * 128 + dv] = r;
}

// ---------------------------------------------------------------------------
extern "C" void kernel_launch(void* const* d_in, const int* in_sizes, int n_in,
                              void* d_out, int out_size, void* d_ws, size_t ws_size,
                              hipStream_t stream) {
  const float* X   = (const float*)d_in[0];
  const float* Wq  = (const float*)d_in[1];
  const float* bq  = (const float*)d_in[2];
  const float* Wk  = (const float*)d_in[3];
  const float* bk  = (const float*)d_in[4];
  const float* Wv  = (const float*)d_in[5];
  const float* bv  = (const float*)d_in[6];
  const float* lam = (const float*)d_in[7];
  float* out = (float*)d_out;

  char* ws = (char*)d_ws;
  size_t off = 0;
  auto alloc = [&](size_t b) { size_t r = off; off += (b + 255) & ~(size_t)255; return r; };
  unsigned short* Xb  = (unsigned short*)(ws + alloc((size_t)NTOK * EDIM * 2));    // 32 MiB
  unsigned short* Wb  = (unsigned short*)(ws + alloc((size_t)FQKV * EDIM * 2));    // 5 MiB
  float*          bc  = (float*)(ws + alloc((size_t)FQKV * 4));
  unsigned short* QK  = (unsigned short*)(ws + alloc((size_t)NTOK * FQK * 2));     // 64 MiB
  unsigned short* Vt  = (unsigned short*)(ws + alloc((size_t)NB * DHEAD * SEQ * 2)); // 16 MiB
  unsigned short* E_c = (unsigned short*)(ws + alloc((size_t)4 * SEQ * SEQ * 2));  // 128 MiB
  float*          ls  = (float*)(ws + alloc((size_t)2 * NTOK * 4));                // 128 KiB
  // O12 (32 MiB) aliases Xb — Xb dead after k_v.
  float* O12 = (float*)Xb;
  // total ws ~245.2 MiB (< 256 MiB)

  k_cvt_x<<<dim3((NTOK * EDIM / 4) / 256), dim3(256), 0, stream>>>(X, Xb);
  k_pack_w<<<dim3((FQKV * EDIM / 4) / 256), dim3(256), 0, stream>>>(Wq, Wk, Wv, Wb);
  k_pack_b<<<dim3(10), dim3(256), 0, stream>>>(bq, bk, bv, bc);
  k_qk<<<dim3(FQK / 128, NTOK / 128), dim3(256), 0, stream>>>(Xb, Wb, bc, QK);
  k_v<<<dim3(SEQ / 128, DHEAD / 128, NB), dim3(256), 0, stream>>>(Xb, Wb, bc, Vt);
  k_zero_f<<<dim3(2 * NTOK / 256), dim3(256), 0, stream>>>(ls);
  for (int b0 = 0; b0 < NB; b0 += 2) {
    k_scores2<<<dim3(SEQ / 128, SEQ / 128, 4), dim3(256), 0, stream>>>(QK, E_c, ls, b0);
    k_pv3<<<dim3(SEQ / 32, 4), dim3(256), 0, stream>>>(E_c, Vt, O12, b0);
    k_combine<<<dim3((2 * SEQ * DHEAD / 4) / 256), dim3(256), 0, stream>>>(O12, ls, lam, out, b0);
  }

  (void)in_sizes; (void)n_in; (void)out_size; (void)ws_size;
}

// Round 7
// 763.544 us; speedup vs baseline: 1.1537x; 1.1537x over previous
//
#include <hip/hip_runtime.h>
#include <cstdint>
#include <cstddef>

// Problem constants
#define NB    4
#define SEQ   4096
#define EDIM  1024
#define DHEAD 512
#define NTOK  (NB * SEQ)     // 16384
#define FQK   2048           // Q and K features only
#define FQKV  2560

typedef __bf16 bf16x8 __attribute__((ext_vector_type(8)));
typedef float  f32x4  __attribute__((ext_vector_type(4)));

__device__ __forceinline__ unsigned short f2bf(float f) {
  union { float f; unsigned int u; } v; v.f = f;
  return (unsigned short)((v.u + 0x7fffu + ((v.u >> 16) & 1u)) >> 16);
}
__device__ __forceinline__ float bf2f(unsigned short h) {
  union { unsigned int u; float f; } v; v.u = ((unsigned int)h) << 16;
  return v.f;
}

// async global->LDS, 16B per lane; LDS dest wave-uniform base, lane i -> base+i*16.
__device__ __forceinline__ void gld_lds16(const void* g, void* l) {
  __builtin_amdgcn_global_load_lds(
      (const __attribute__((address_space(1))) unsigned int*)g,
      (__attribute__((address_space(3))) unsigned int*)l, 16, 0, 0);
}

// ---------------------------------------------------------------------------
// m97-style GEMM-BT core: C(128x128) = A(128xK) * B(128xK)^T, bf16 in, fp32 acc.
// ---------------------------------------------------------------------------
template <class Epi>
__device__ __forceinline__ void gemm_bt_core(
    const unsigned short* __restrict__ A, const unsigned short* __restrict__ B,
    int K, int lda, int ldb, int m0, int n0, Epi epi) {
  __shared__ __align__(16) unsigned short As[128 * 32];
  __shared__ __align__(16) unsigned short Bs[128 * 32];
  const int t = threadIdx.x;
  const int w = t >> 6;
  const int lane = t & 63;
  const int wr = w >> 1, wc = w & 1;

  f32x4 acc[4][4];
#pragma unroll
  for (int i = 0; i < 4; ++i)
#pragma unroll
    for (int j = 0; j < 4; ++j) acc[i][j] = f32x4{0.f, 0.f, 0.f, 0.f};

  const int c0 = (w * 2) * 64 + lane;
  const int c1 = (w * 2 + 1) * 64 + lane;
  const int r0 = c0 >> 2, col0 = (c0 & 3) * 8;
  const int r1 = c1 >> 2, col1 = (c1 & 3) * 8;
  unsigned short* ldsA0 = &As[(w * 2) * 512];
  unsigned short* ldsA1 = &As[(w * 2 + 1) * 512];
  unsigned short* ldsB0 = &Bs[(w * 2) * 512];
  unsigned short* ldsB1 = &Bs[(w * 2 + 1) * 512];
  const unsigned short* gA0 = A + (size_t)(m0 + r0) * lda + col0;
  const unsigned short* gA1 = A + (size_t)(m0 + r1) * lda + col1;
  const unsigned short* gB0 = B + (size_t)(n0 + r0) * ldb + col0;
  const unsigned short* gB1 = B + (size_t)(n0 + r1) * ldb + col1;

  for (int kt = 0; kt < K; kt += 32) {
    gld_lds16(gA0 + kt, ldsA0);
    gld_lds16(gA1 + kt, ldsA1);
    gld_lds16(gB0 + kt, ldsB0);
    gld_lds16(gB1 + kt, ldsB1);
    __syncthreads();

    bf16x8 af[4], bfr[4];
#pragma unroll
    for (int tm = 0; tm < 4; ++tm) {
      int r = wr * 64 + tm * 16 + (lane & 15);
      af[tm] = *(const bf16x8*)&As[r * 32 + (lane >> 4) * 8];
    }
#pragma unroll
    for (int tn = 0; tn < 4; ++tn) {
      int r = wc * 64 + tn * 16 + (lane & 15);
      bfr[tn] = *(const bf16x8*)&Bs[r * 32 + (lane >> 4) * 8];
    }
#pragma unroll
    for (int tm = 0; tm < 4; ++tm)
#pragma unroll
      for (int tn = 0; tn < 4; ++tn)
        acc[tm][tn] = __builtin_amdgcn_mfma_f32_16x16x32_bf16(
            af[tm], bfr[tn], acc[tm][tn], 0, 0, 0);
    __syncthreads();
  }
  epi(acc, wr, wc, lane);
}

// ---------------------------------------------------------------------------
// Utility kernels
// ---------------------------------------------------------------------------
__global__ void k_cvt_x(const float* __restrict__ X, unsigned short* __restrict__ Xb) {
  int i = blockIdx.x * blockDim.x + threadIdx.x;
  float4 v = ((const float4*)X)[i];
  ushort4 o;
  o.x = f2bf(v.x); o.y = f2bf(v.y); o.z = f2bf(v.z); o.w = f2bf(v.w);
  ((ushort4*)Xb)[i] = o;
}

__global__ void k_pack_w(const float* __restrict__ Wq, const float* __restrict__ Wk,
                         const float* __restrict__ Wv, unsigned short* __restrict__ Wb) {
  int i = blockIdx.x * blockDim.x + threadIdx.x;
  int idx = i * 4;
  int f = idx >> 10, e = idx & 1023;
  const float* src = (f < 1024) ? (Wq + (size_t)f * 1024)
                   : (f < 2048) ? (Wk + (size_t)(f - 1024) * 1024)
                                : (Wv + (size_t)(f - 2048) * 1024);
  float4 v = *(const float4*)(src + e);
  ushort4 o;
  o.x = f2bf(v.x); o.y = f2bf(v.y); o.z = f2bf(v.z); o.w = f2bf(v.w);
  ((ushort4*)Wb)[i] = o;
}

__global__ void k_pack_b(const float* __restrict__ bq, const float* __restrict__ bk,
                         const float* __restrict__ bv, float* __restrict__ bc) {
  int f = blockIdx.x * blockDim.x + threadIdx.x;
  if (f < FQKV)
    bc[f] = (f < 1024) ? bq[f] : (f < 2048) ? bk[f - 1024] : bv[f - 2048];
}

__global__ void k_zero_f(float* __restrict__ p) {
  int i = blockIdx.x * blockDim.x + threadIdx.x;
  p[i] = 0.f;
}

// ---------------------------------------------------------------------------
// GEMM kernels
// ---------------------------------------------------------------------------
// QK[n][f] = sum_e Xb[n][e]*Wb[f][e] + bc[f], f in [0,2048)   (bf16 out)
__global__ __launch_bounds__(256) void k_qk(const unsigned short* __restrict__ Xb,
                                            const unsigned short* __restrict__ Wb,
                                            const float* __restrict__ bc,
                                            unsigned short* __restrict__ QK) {
  __shared__ __align__(16) unsigned short Ps[128 * 136];
  const int m0 = blockIdx.y * 128, n0 = blockIdx.x * 128;
  gemm_bt_core(Xb, Wb, EDIM, EDIM, EDIM, m0, n0,
    [&](f32x4 (&acc)[4][4], int wr, int wc, int lane) {
      const int w = wr * 2 + wc;
#pragma unroll
      for (int tm = 0; tm < 4; ++tm)
#pragma unroll
        for (int tn = 0; tn < 4; ++tn) {
          int kc = wc * 64 + tn * 16 + (lane & 15);
          float bias = bc[n0 + kc];
#pragma unroll
          for (int i = 0; i < 4; ++i) {
            int ql = wr * 64 + tm * 16 + (lane >> 4) * 4 + i;
            Ps[ql * 136 + kc] = f2bf(acc[tm][tn][i] + bias);
          }
        }
      __syncthreads();
#pragma unroll
      for (int j = 0; j < 8; ++j) {
        int row = w * 32 + j * 4 + (lane >> 4);
        int col = (lane & 15) * 8;
        uint4 v = *(const uint4*)&Ps[row * 136 + col];
        *(uint4*)&QK[(size_t)(m0 + row) * FQK + n0 + col] = v;
      }
    });
}

// Vt[b][d][s] = sum_e Wv[d][e]*Xb[b*SEQ+s][e] + bv[d]   (bf16, transposed V)
__global__ __launch_bounds__(256) void k_v(const unsigned short* __restrict__ Xb,
                                           const unsigned short* __restrict__ Wb,
                                           const float* __restrict__ bc,
                                           unsigned short* __restrict__ Vt) {
  const int b = blockIdx.z;
  const int m0 = blockIdx.y * 128;  // d tile
  const int n0 = blockIdx.x * 128;  // s tile
  const unsigned short* A = Wb + (size_t)2048 * EDIM;
  const unsigned short* B = Xb + (size_t)b * SEQ * EDIM;
  unsigned short* Vb = Vt + (size_t)b * DHEAD * SEQ;
  gemm_bt_core(A, B, EDIM, EDIM, EDIM, m0, n0,
    [&](f32x4 (&acc)[4][4], int wr, int wc, int lane) {
#pragma unroll
      for (int tm = 0; tm < 4; ++tm)
#pragma unroll
        for (int tn = 0; tn < 4; ++tn) {
          int s = n0 + wc * 64 + tn * 16 + (lane & 15);
#pragma unroll
          for (int i = 0; i < 4; ++i) {
            int d = m0 + wr * 64 + tm * 16 + (lane >> 4) * 4 + i;
            Vb[(size_t)d * SEQ + s] = f2bf(acc[tm][tn][i] + bc[2048 + d]);
          }
        }
    });
}

// Chunk of 2 batches, both which: z = blockIdx.z -> (rb=z>>1, which=z&1).
__global__ __launch_bounds__(256) void k_scores2(const unsigned short* __restrict__ QK,
                                                 unsigned short* __restrict__ E_c,
                                                 float* __restrict__ ls, int b0) {
  __shared__ __align__(16) unsigned short Ps[128 * 136];
  const int z = blockIdx.z;
  const int rb = z >> 1, which = z & 1;
  const int b = b0 + rb;
  const int m0 = blockIdx.y * 128;  // q tile
  const int n0 = blockIdx.x * 128;  // k tile
  const unsigned short* Aq = QK + (size_t)b * SEQ * FQK + which * 512;
  const unsigned short* Bk = QK + (size_t)b * SEQ * FQK + 1024 + which * 512;
  unsigned short* Eb = E_c + (size_t)z * SEQ * SEQ;
  float* lr = ls + (size_t)which * NTOK + (size_t)b * SEQ;
  gemm_bt_core(Aq, Bk, 512, FQK, FQK, m0, n0,
    [&](f32x4 (&acc)[4][4], int wr, int wc, int lane) {
      const float scale = 0.04419417382415922f;  // 1/sqrt(512)
      const int w = wr * 2 + wc;
      float rs[4][4];
#pragma unroll
      for (int tm = 0; tm < 4; ++tm)
#pragma unroll
        for (int i = 0; i < 4; ++i) rs[tm][i] = 0.f;
#pragma unroll
      for (int tm = 0; tm < 4; ++tm)
#pragma unroll
        for (int tn = 0; tn < 4; ++tn) {
          int kc = wc * 64 + tn * 16 + (lane & 15);
#pragma unroll
          for (int i = 0; i < 4; ++i) {
            int ql = wr * 64 + tm * 16 + (lane >> 4) * 4 + i;
            float e = __expf(acc[tm][tn][i] * scale);
            unsigned short eb = f2bf(e);
            Ps[ql * 136 + kc] = eb;
            rs[tm][i] += bf2f(eb);
          }
        }
#pragma unroll
      for (int tm = 0; tm < 4; ++tm)
#pragma unroll
        for (int i = 0; i < 4; ++i) {
          float v = rs[tm][i];
          v += __shfl_xor(v, 1);
          v += __shfl_xor(v, 2);
          v += __shfl_xor(v, 4);
          v += __shfl_xor(v, 8);
          rs[tm][i] = v;
        }
      if ((lane & 15) == 0) {
#pragma unroll
        for (int tm = 0; tm < 4; ++tm)
#pragma unroll
          for (int i = 0; i < 4; ++i) {
            int q = m0 + wr * 64 + tm * 16 + (lane >> 4) * 4 + i;
            atomicAdd(&lr[q], rs[tm][i]);
          }
      }
      __syncthreads();
#pragma unroll
      for (int j = 0; j < 8; ++j) {
        int row = w * 32 + j * 4 + (lane >> 4);
        int col = (lane & 15) * 8;
        uint4 v = *(const uint4*)&Ps[row * 136 + col];
        *(uint4*)&Eb[(size_t)(m0 + row) * SEQ + n0 + col] = v;
      }
    });
}

// O12[z][q][d] = sum_k E_c[z][q][k] * Vt[b][d][k]  (fp32, un-normalized).
// Tile 64q x 256d, 4 waves side-by-side (each 64x64, acc[4][4] m97 balance).
// 1D grid 512; XCD-aware decode: z = (bid>>1)&3 so each z's 4 MiB Vt slice
// maps to 2 adjacent XCD slots -> Vt re-reads served by per-XCD L2.
__global__ __launch_bounds__(256) void k_pv4(const unsigned short* __restrict__ E_c,
                                             const unsigned short* __restrict__ Vt,
                                             float* __restrict__ O12, int b0) {
  __shared__ __align__(16) unsigned short As[64 * 32];    // 4 KB
  __shared__ __align__(16) unsigned short Bs[256 * 32];   // 16 KB
  const int bid = blockIdx.x;               // [0, 512)
  const int z = (bid >> 1) & 3;             // 2 adjacent xcd-slots per z
  const int e = (bid & 1) | ((bid >> 3) << 1);  // [0, 128)
  const int q0 = (e >> 1) * 64;             // 64 q-tiles
  const int n0 = (e & 1) * 256;             // 2 d-tiles
  const int b = b0 + (z >> 1);
  const unsigned short* A = E_c + (size_t)z * SEQ * SEQ;   // rows q0..q0+63
  const unsigned short* Bv = Vt + (size_t)b * DHEAD * SEQ; // rows n0..n0+255
  float* Ob = O12 + (size_t)z * SEQ * DHEAD;
  const int t = threadIdx.x, w = t >> 6, lane = t & 63;

  f32x4 acc[4][4];
#pragma unroll
  for (int i = 0; i < 4; ++i)
#pragma unroll
    for (int j = 0; j < 4; ++j) acc[i][j] = f32x4{0.f, 0.f, 0.f, 0.f};

  // A staging: 64x32 = 256 chunks of 16B; wave w does chunk w*64+lane (1 gld).
  const int ca = w * 64 + lane;
  const unsigned short* gA = A + (size_t)(q0 + (ca >> 2)) * SEQ + (ca & 3) * 8;
  unsigned short* ldsA = As + (w * 64) * 8;   // wave-uniform
  // B staging: 256x32 = 1024 chunks; wave w does [w*256, w*256+256): 4 glds.
  const unsigned short* gB[4];
  unsigned short* ldsB[4];
#pragma unroll
  for (int g = 0; g < 4; ++g) {
    int c = w * 256 + g * 64 + lane;
    gB[g] = Bv + (size_t)(n0 + (c >> 2)) * SEQ + (c & 3) * 8;
    ldsB[g] = Bs + (w * 256 + g * 64) * 8;    // wave-uniform
  }

  for (int kt = 0; kt < SEQ; kt += 32) {
    gld_lds16(gA + kt, ldsA);
#pragma unroll
    for (int g = 0; g < 4; ++g) gld_lds16(gB[g] + kt, ldsB[g]);
    __syncthreads();

    bf16x8 af[4], bfr[4];
#pragma unroll
    for (int tm = 0; tm < 4; ++tm) {
      int r = tm * 16 + (lane & 15);
      af[tm] = *(const bf16x8*)&As[r * 32 + (lane >> 4) * 8];
    }
#pragma unroll
    for (int tn = 0; tn < 4; ++tn) {
      int r = w * 64 + tn * 16 + (lane & 15);
      bfr[tn] = *(const bf16x8*)&Bs[r * 32 + (lane >> 4) * 8];
    }
#pragma unroll
    for (int tm = 0; tm < 4; ++tm)
#pragma unroll
      for (int tn = 0; tn < 4; ++tn)
        acc[tm][tn] = __builtin_amdgcn_mfma_f32_16x16x32_bf16(
            af[tm], bfr[tn], acc[tm][tn], 0, 0, 0);
    __syncthreads();
  }

#pragma unroll
  for (int tm = 0; tm < 4; ++tm)
#pragma unroll
    for (int tn = 0; tn < 4; ++tn) {
      int d = n0 + w * 64 + tn * 16 + (lane & 15);
#pragma unroll
      for (int i = 0; i < 4; ++i) {
        int q = q0 + tm * 16 + (lane >> 4) * 4 + i;
        Ob[(size_t)q * DHEAD + d] = acc[tm][tn][i];
      }
    }
}

// Chunk combine: out[b0+rb] = O12[rb*2+0]/l1 - lambda * O12[rb*2+1]/l2
__global__ void k_combine(const float* __restrict__ O12, const float* __restrict__ ls,
                          const float* __restrict__ lam, float* __restrict__ out, int b0) {
  int i = blockIdx.x * blockDim.x + threadIdx.x;
  float lambda = expf(lam[0]) + 0.05f;
  int gq = i >> 7;
  int rb = gq >> 12;
  int q = gq & 4095;
  int dv = i & 127;
  int b = b0 + rb;
  float inv1 = 1.f / ls[(size_t)b * SEQ + q];
  float inv2 = lambda / ls[NTOK + (size_t)b * SEQ + q];
  size_t ai = (size_t)(rb * 2) * (SEQ * 128) + (size_t)q * 128 + dv;
  float4 a = ((const float4*)O12)[ai];
  float4 c = ((const float4*)O12)[ai + SEQ * 128];
  float4 r;
  r.x = a.x * inv1 - c.x * inv2;
  r.y = a.y * inv1 - c.y * inv2;
  r.z = a.z * inv1 - c.z * inv2;
  r.w = a.w * inv1 - c.w * inv2;
  ((float4*)out)[(size_t)(b * SEQ + q) * 128 + dv] = r;
}

// ---------------------------------------------------------------------------
extern "C" void kernel_launch(void* const* d_in, const int* in_sizes, int n_in,
                              void* d_out, int out_size, void* d_ws, size_t ws_size,
                              hipStream_t stream) {
  const float* X   = (const float*)d_in[0];
  const float* Wq  = (const float*)d_in[1];
  const float* bq  = (const float*)d_in[2];
  const float* Wk  = (const float*)d_in[3];
  const float* bk  = (const float*)d_in[4];
  const float* Wv  = (const float*)d_in[5];
  const float* bv  = (const float*)d_in[6];
  const float* lam = (const float*)d_in[7];
  float* out = (float*)d_out;

  char* ws = (char*)d_ws;
  size_t off = 0;
  auto alloc = [&](size_t b) { size_t r = off; off += (b + 255) & ~(size_t)255; return r; };
  unsigned short* Xb  = (unsigned short*)(ws + alloc((size_t)NTOK * EDIM * 2));    // 32 MiB
  unsigned short* Wb  = (unsigned short*)(ws + alloc((size_t)FQKV * EDIM * 2));    // 5 MiB
  float*          bc  = (float*)(ws + alloc((size_t)FQKV * 4));
  unsigned short* QK  = (unsigned short*)(ws + alloc((size_t)NTOK * FQK * 2));     // 64 MiB
  unsigned short* Vt  = (unsigned short*)(ws + alloc((size_t)NB * DHEAD * SEQ * 2)); // 16 MiB
  unsigned short* E_c = (unsigned short*)(ws + alloc((size_t)4 * SEQ * SEQ * 2));  // 128 MiB
  float*          ls  = (float*)(ws + alloc((size_t)2 * NTOK * 4));                // 128 KiB
  float* O12 = (float*)Xb;  // 32 MiB alias; Xb dead after k_v
  // total ws ~245.2 MiB (< 256 MiB)

  k_cvt_x<<<dim3((NTOK * EDIM / 4) / 256), dim3(256), 0, stream>>>(X, Xb);
  k_pack_w<<<dim3((FQKV * EDIM / 4) / 256), dim3(256), 0, stream>>>(Wq, Wk, Wv, Wb);
  k_pack_b<<<dim3(10), dim3(256), 0, stream>>>(bq, bk, bv, bc);
  k_qk<<<dim3(FQK / 128, NTOK / 128), dim3(256), 0, stream>>>(Xb, Wb, bc, QK);
  k_v<<<dim3(SEQ / 128, DHEAD / 128, NB), dim3(256), 0, stream>>>(Xb, Wb, bc, Vt);
  k_zero_f<<<dim3(2 * NTOK / 256), dim3(256), 0, stream>>>(ls);
  for (int b0 = 0; b0 < NB; b0 += 2) {
    k_scores2<<<dim3(SEQ / 128, SEQ / 128, 4), dim3(256), 0, stream>>>(QK, E_c, ls, b0);
    k_pv4<<<dim3(512), dim3(256), 0, stream>>>(E_c, Vt, O12, b0);
    k_combine<<<dim3((2 * SEQ * DHEAD / 4) / 256), dim3(256), 0, stream>>>(O12, ls, lam, out, b0);
  }

  (void)in_sizes; (void)n_in; (void)out_size; (void)ws_size;
}

// Round 9
// 732.589 us; speedup vs baseline: 1.2025x; 1.0423x over previous
//
#include <hip/hip_runtime.h>
#include <cstdint>
#include <cstddef>

// Problem constants
#define NB    4
#define SEQ   4096
#define EDIM  1024
#define DHEAD 512
#define NTOK  (NB * SEQ)     // 16384
#define FQK   2048           // Q and K features only
#define FQKV  2560

typedef __bf16 bf16x8 __attribute__((ext_vector_type(8)));
typedef float  f32x4  __attribute__((ext_vector_type(4)));

__device__ __forceinline__ unsigned short f2bf(float f) {
  union { float f; unsigned int u; } v; v.f = f;
  return (unsigned short)((v.u + 0x7fffu + ((v.u >> 16) & 1u)) >> 16);
}
__device__ __forceinline__ float bf2f(unsigned short h) {
  union { unsigned int u; float f; } v; v.u = ((unsigned int)h) << 16;
  return v.f;
}

// async global->LDS, 16B per lane; LDS dest wave-uniform base, lane i -> base+i*16.
__device__ __forceinline__ void gld_lds16(const void* g, void* l) {
  __builtin_amdgcn_global_load_lds(
      (const __attribute__((address_space(1))) unsigned int*)g,
      (__attribute__((address_space(3))) unsigned int*)l, 16, 0, 0);
}

// ---------------------------------------------------------------------------
// m97-style GEMM-BT core: C(128x128) = A(128xK) * B(128xK)^T, bf16 in, fp32 acc.
// ---------------------------------------------------------------------------
template <class Epi>
__device__ __forceinline__ void gemm_bt_core(
    const unsigned short* __restrict__ A, const unsigned short* __restrict__ B,
    int K, int lda, int ldb, int m0, int n0, Epi epi) {
  __shared__ __align__(16) unsigned short As[128 * 32];
  __shared__ __align__(16) unsigned short Bs[128 * 32];
  const int t = threadIdx.x;
  const int w = t >> 6;
  const int lane = t & 63;
  const int wr = w >> 1, wc = w & 1;

  f32x4 acc[4][4];
#pragma unroll
  for (int i = 0; i < 4; ++i)
#pragma unroll
    for (int j = 0; j < 4; ++j) acc[i][j] = f32x4{0.f, 0.f, 0.f, 0.f};

  const int c0 = (w * 2) * 64 + lane;
  const int c1 = (w * 2 + 1) * 64 + lane;
  const int r0 = c0 >> 2, col0 = (c0 & 3) * 8;
  const int r1 = c1 >> 2, col1 = (c1 & 3) * 8;
  unsigned short* ldsA0 = &As[(w * 2) * 512];
  unsigned short* ldsA1 = &As[(w * 2 + 1) * 512];
  unsigned short* ldsB0 = &Bs[(w * 2) * 512];
  unsigned short* ldsB1 = &Bs[(w * 2 + 1) * 512];
  const unsigned short* gA0 = A + (size_t)(m0 + r0) * lda + col0;
  const unsigned short* gA1 = A + (size_t)(m0 + r1) * lda + col1;
  const unsigned short* gB0 = B + (size_t)(n0 + r0) * ldb + col0;
  const unsigned short* gB1 = B + (size_t)(n0 + r1) * ldb + col1;

  for (int kt = 0; kt < K; kt += 32) {
    gld_lds16(gA0 + kt, ldsA0);
    gld_lds16(gA1 + kt, ldsA1);
    gld_lds16(gB0 + kt, ldsB0);
    gld_lds16(gB1 + kt, ldsB1);
    __syncthreads();

    bf16x8 af[4], bfr[4];
#pragma unroll
    for (int tm = 0; tm < 4; ++tm) {
      int r = wr * 64 + tm * 16 + (lane & 15);
      af[tm] = *(const bf16x8*)&As[r * 32 + (lane >> 4) * 8];
    }
#pragma unroll
    for (int tn = 0; tn < 4; ++tn) {
      int r = wc * 64 + tn * 16 + (lane & 15);
      bfr[tn] = *(const bf16x8*)&Bs[r * 32 + (lane >> 4) * 8];
    }
#pragma unroll
    for (int tm = 0; tm < 4; ++tm)
#pragma unroll
      for (int tn = 0; tn < 4; ++tn)
        acc[tm][tn] = __builtin_amdgcn_mfma_f32_16x16x32_bf16(
            af[tm], bfr[tn], acc[tm][tn], 0, 0, 0);
    __syncthreads();
  }
  epi(acc, wr, wc, lane);
}

// ---------------------------------------------------------------------------
// Utility kernels
// ---------------------------------------------------------------------------
__global__ void k_cvt_x(const float* __restrict__ X, unsigned short* __restrict__ Xb) {
  int i = blockIdx.x * blockDim.x + threadIdx.x;
  float4 v = ((const float4*)X)[i];
  ushort4 o;
  o.x = f2bf(v.x); o.y = f2bf(v.y); o.z = f2bf(v.z); o.w = f2bf(v.w);
  ((ushort4*)Xb)[i] = o;
}

__global__ void k_pack_w(const float* __restrict__ Wq, const float* __restrict__ Wk,
                         const float* __restrict__ Wv, unsigned short* __restrict__ Wb) {
  int i = blockIdx.x * blockDim.x + threadIdx.x;
  int idx = i * 4;
  int f = idx >> 10, e = idx & 1023;
  const float* src = (f < 1024) ? (Wq + (size_t)f * 1024)
                   : (f < 2048) ? (Wk + (size_t)(f - 1024) * 1024)
                                : (Wv + (size_t)(f - 2048) * 1024);
  float4 v = *(const float4*)(src + e);
  ushort4 o;
  o.x = f2bf(v.x); o.y = f2bf(v.y); o.z = f2bf(v.z); o.w = f2bf(v.w);
  ((ushort4*)Wb)[i] = o;
}

__global__ void k_pack_b(const float* __restrict__ bq, const float* __restrict__ bk,
                         const float* __restrict__ bv, float* __restrict__ bc) {
  int f = blockIdx.x * blockDim.x + threadIdx.x;
  if (f < FQKV)
    bc[f] = (f < 1024) ? bq[f] : (f < 2048) ? bk[f - 1024] : bv[f - 2048];
}

__global__ void k_zero_f(float* __restrict__ p) {
  int i = blockIdx.x * blockDim.x + threadIdx.x;
  p[i] = 0.f;
}

// ---------------------------------------------------------------------------
// GEMM kernels
// ---------------------------------------------------------------------------
// QK[n][f] = sum_e Xb[n][e]*Wb[f][e] + bc[f], f in [0,2048)   (bf16 out)
__global__ __launch_bounds__(256) void k_qk(const unsigned short* __restrict__ Xb,
                                            const unsigned short* __restrict__ Wb,
                                            const float* __restrict__ bc,
                                            unsigned short* __restrict__ QK) {
  __shared__ __align__(16) unsigned short Ps[128 * 136];
  const int m0 = blockIdx.y * 128, n0 = blockIdx.x * 128;
  gemm_bt_core(Xb, Wb, EDIM, EDIM, EDIM, m0, n0,
    [&](f32x4 (&acc)[4][4], int wr, int wc, int lane) {
      const int w = wr * 2 + wc;
#pragma unroll
      for (int tm = 0; tm < 4; ++tm)
#pragma unroll
        for (int tn = 0; tn < 4; ++tn) {
          int kc = wc * 64 + tn * 16 + (lane & 15);
          float bias = bc[n0 + kc];
#pragma unroll
          for (int i = 0; i < 4; ++i) {
            int ql = wr * 64 + tm * 16 + (lane >> 4) * 4 + i;
            Ps[ql * 136 + kc] = f2bf(acc[tm][tn][i] + bias);
          }
        }
      __syncthreads();
#pragma unroll
      for (int j = 0; j < 8; ++j) {
        int row = w * 32 + j * 4 + (lane >> 4);
        int col = (lane & 15) * 8;
        uint4 v = *(const uint4*)&Ps[row * 136 + col];
        *(uint4*)&QK[(size_t)(m0 + row) * FQK + n0 + col] = v;
      }
    });
}

// Vt[b][d][s] = sum_e Wv[d][e]*Xb[b*SEQ+s][e] + bv[d]   (bf16, transposed V)
__global__ __launch_bounds__(256) void k_v(const unsigned short* __restrict__ Xb,
                                           const unsigned short* __restrict__ Wb,
                                           const float* __restrict__ bc,
                                           unsigned short* __restrict__ Vt) {
  const int b = blockIdx.z;
  const int m0 = blockIdx.y * 128;  // d tile
  const int n0 = blockIdx.x * 128;  // s tile
  const unsigned short* A = Wb + (size_t)2048 * EDIM;
  const unsigned short* B = Xb + (size_t)b * SEQ * EDIM;
  unsigned short* Vb = Vt + (size_t)b * DHEAD * SEQ;
  gemm_bt_core(A, B, EDIM, EDIM, EDIM, m0, n0,
    [&](f32x4 (&acc)[4][4], int wr, int wc, int lane) {
#pragma unroll
      for (int tm = 0; tm < 4; ++tm)
#pragma unroll
        for (int tn = 0; tn < 4; ++tn) {
          int s = n0 + wc * 64 + tn * 16 + (lane & 15);
#pragma unroll
          for (int i = 0; i < 4; ++i) {
            int d = m0 + wr * 64 + tm * 16 + (lane >> 4) * 4 + i;
            Vb[(size_t)d * SEQ + s] = f2bf(acc[tm][tn][i] + bc[2048 + d]);
          }
        }
    });
}

// Chunk of 2 batches, both which: z = blockIdx.z -> (rb=z>>1, which=z&1).
// 256q x 128k tile, 512 threads = 8 waves (wr = w>>1 in q, wc = w&1 in k),
// each wave 64x64 / acc[4][4]. No LDS epilogue round-trip.
__global__ __launch_bounds__(512) void k_scores3(const unsigned short* __restrict__ QK,
                                                 unsigned short* __restrict__ E_c,
                                                 float* __restrict__ ls, int b0) {
  __shared__ __align__(16) unsigned short As[256 * 32];   // 16 KB
  __shared__ __align__(16) unsigned short Bs[128 * 32];   // 8 KB
  const int z = blockIdx.z;
  const int rb = z >> 1, which = z & 1;
  const int b = b0 + rb;
  const int m0 = blockIdx.y * 256;  // q tile
  const int n0 = blockIdx.x * 128;  // k tile
  const unsigned short* Aq = QK + (size_t)b * SEQ * FQK + which * 512;
  const unsigned short* Bk = QK + (size_t)b * SEQ * FQK + 1024 + which * 512;
  unsigned short* Eb = E_c + (size_t)z * SEQ * SEQ;
  float* lr = ls + (size_t)which * NTOK + (size_t)b * SEQ;
  const int t = threadIdx.x, w = t >> 6, lane = t & 63;
  const int wr = w >> 1, wc = w & 1;

  f32x4 acc[4][4];
#pragma unroll
  for (int i = 0; i < 4; ++i)
#pragma unroll
    for (int j = 0; j < 4; ++j) acc[i][j] = f32x4{0.f, 0.f, 0.f, 0.f};

  // Staging: As 256x32 = 1024 chunks of 16B, wave w does chunks w*128+{0,64}+lane.
  // Bs 128x32 = 512 chunks, wave w does chunk w*64+lane. 3 gld per wave per iter.
  const int cA0 = w * 128 + lane;
  const int cA1 = w * 128 + 64 + lane;
  const int cB  = w * 64 + lane;
  const unsigned short* gA0 = Aq + (size_t)(m0 + (cA0 >> 2)) * FQK + (cA0 & 3) * 8;
  const unsigned short* gA1 = Aq + (size_t)(m0 + (cA1 >> 2)) * FQK + (cA1 & 3) * 8;
  const unsigned short* gB  = Bk + (size_t)(n0 + (cB >> 2)) * FQK + (cB & 3) * 8;
  unsigned short* ldsA0 = As + (w * 128) * 8;        // wave-uniform
  unsigned short* ldsA1 = As + (w * 128 + 64) * 8;
  unsigned short* ldsB  = Bs + (w * 64) * 8;

  for (int kt = 0; kt < 512; kt += 32) {
    gld_lds16(gA0 + kt, ldsA0);
    gld_lds16(gA1 + kt, ldsA1);
    gld_lds16(gB + kt, ldsB);
    __syncthreads();

    bf16x8 af[4], bfr[4];
#pragma unroll
    for (int tm = 0; tm < 4; ++tm) {
      int r = wr * 64 + tm * 16 + (lane & 15);
      af[tm] = *(const bf16x8*)&As[r * 32 + (lane >> 4) * 8];
    }
#pragma unroll
    for (int tn = 0; tn < 4; ++tn) {
      int r = wc * 64 + tn * 16 + (lane & 15);
      bfr[tn] = *(const bf16x8*)&Bs[r * 32 + (lane >> 4) * 8];
    }
#pragma unroll
    for (int tm = 0; tm < 4; ++tm)
#pragma unroll
      for (int tn = 0; tn < 4; ++tn)
        acc[tm][tn] = __builtin_amdgcn_mfma_f32_16x16x32_bf16(
            af[tm], bfr[tn], acc[tm][tn], 0, 0, 0);
    __syncthreads();
  }

  // Epilogue: exp + direct stores (16 lanes x 2B = 32B segments) + row sums.
  const float scale = 0.04419417382415922f;  // 1/sqrt(512)
  float rs[4][4];
#pragma unroll
  for (int tm = 0; tm < 4; ++tm)
#pragma unroll
    for (int i = 0; i < 4; ++i) rs[tm][i] = 0.f;
#pragma unroll
  for (int tm = 0; tm < 4; ++tm)
#pragma unroll
    for (int tn = 0; tn < 4; ++tn) {
      int k = n0 + wc * 64 + tn * 16 + (lane & 15);
#pragma unroll
      for (int i = 0; i < 4; ++i) {
        int q = m0 + wr * 64 + tm * 16 + (lane >> 4) * 4 + i;
        float e = __expf(acc[tm][tn][i] * scale);
        unsigned short eb = f2bf(e);
        Eb[(size_t)q * SEQ + k] = eb;
        rs[tm][i] += bf2f(eb);  // sum rounded value for consistency
      }
    }
#pragma unroll
  for (int tm = 0; tm < 4; ++tm)
#pragma unroll
    for (int i = 0; i < 4; ++i) {
      float v = rs[tm][i];
      v += __shfl_xor(v, 1);
      v += __shfl_xor(v, 2);
      v += __shfl_xor(v, 4);
      v += __shfl_xor(v, 8);
      rs[tm][i] = v;
    }
  if ((lane & 15) == 0) {
#pragma unroll
    for (int tm = 0; tm < 4; ++tm)
#pragma unroll
      for (int i = 0; i < 4; ++i) {
        int q = m0 + wr * 64 + tm * 16 + (lane >> 4) * 4 + i;
        atomicAdd(&lr[q], rs[tm][i]);
      }
  }
}

// O12[z][q][d] = sum_k E_c[z][q][k] * Vt[b][d][k]  (fp32, un-normalized).
// Tile 64q x 256d, 4 waves side-by-side; 1D grid 512 with XCD-aware decode.
__global__ __launch_bounds__(256) void k_pv4(const unsigned short* __restrict__ E_c,
                                             const unsigned short* __restrict__ Vt,
                                             float* __restrict__ O12, int b0) {
  __shared__ __align__(16) unsigned short As[64 * 32];    // 4 KB
  __shared__ __align__(16) unsigned short Bs[256 * 32];   // 16 KB
  const int bid = blockIdx.x;               // [0, 512)
  const int z = (bid >> 1) & 3;             // 2 adjacent xcd-slots per z
  const int e = (bid & 1) | ((bid >> 3) << 1);  // [0, 128)
  const int q0 = (e >> 1) * 64;             // 64 q-tiles
  const int n0 = (e & 1) * 256;             // 2 d-tiles
  const int b = b0 + (z >> 1);
  const unsigned short* A = E_c + (size_t)z * SEQ * SEQ;   // rows q0..q0+63
  const unsigned short* Bv = Vt + (size_t)b * DHEAD * SEQ; // rows n0..n0+255
  float* Ob = O12 + (size_t)z * SEQ * DHEAD;
  const int t = threadIdx.x, w = t >> 6, lane = t & 63;

  f32x4 acc[4][4];
#pragma unroll
  for (int i = 0; i < 4; ++i)
#pragma unroll
    for (int j = 0; j < 4; ++j) acc[i][j] = f32x4{0.f, 0.f, 0.f, 0.f};

  const int ca = w * 64 + lane;
  const unsigned short* gA = A + (size_t)(q0 + (ca >> 2)) * SEQ + (ca & 3) * 8;
  unsigned short* ldsA = As + (w * 64) * 8;   // wave-uniform
  const unsigned short* gB[4];
  unsigned short* ldsB[4];
#pragma unroll
  for (int g = 0; g < 4; ++g) {
    int c = w * 256 + g * 64 + lane;
    gB[g] = Bv + (size_t)(n0 + (c >> 2)) * SEQ + (c & 3) * 8;
    ldsB[g] = Bs + (w * 256 + g * 64) * 8;    // wave-uniform
  }

  for (int kt = 0; kt < SEQ; kt += 32) {
    gld_lds16(gA + kt, ldsA);
#pragma unroll
    for (int g = 0; g < 4; ++g) gld_lds16(gB[g] + kt, ldsB[g]);
    __syncthreads();

    bf16x8 af[4], bfr[4];
#pragma unroll
    for (int tm = 0; tm < 4; ++tm) {
      int r = tm * 16 + (lane & 15);
      af[tm] = *(const bf16x8*)&As[r * 32 + (lane >> 4) * 8];
    }
#pragma unroll
    for (int tn = 0; tn < 4; ++tn) {
      int r = w * 64 + tn * 16 + (lane & 15);
      bfr[tn] = *(const bf16x8*)&Bs[r * 32 + (lane >> 4) * 8];
    }
#pragma unroll
    for (int tm = 0; tm < 4; ++tm)
#pragma unroll
      for (int tn = 0; tn < 4; ++tn)
        acc[tm][tn] = __builtin_amdgcn_mfma_f32_16x16x32_bf16(
            af[tm], bfr[tn], acc[tm][tn], 0, 0, 0);
    __syncthreads();
  }

#pragma unroll
  for (int tm = 0; tm < 4; ++tm)
#pragma unroll
    for (int tn = 0; tn < 4; ++tn) {
      int d = n0 + w * 64 + tn * 16 + (lane & 15);
#pragma unroll
      for (int i = 0; i < 4; ++i) {
        int q = q0 + tm * 16 + (lane >> 4) * 4 + i;
        Ob[(size_t)q * DHEAD + d] = acc[tm][tn][i];
      }
    }
}

// Chunk combine: out[b0+rb] = O12[rb*2+0]/l1 - lambda * O12[rb*2+1]/l2
__global__ void k_combine(const float* __restrict__ O12, const float* __restrict__ ls,
                          const float* __restrict__ lam, float* __restrict__ out, int b0) {
  int i = blockIdx.x * blockDim.x + threadIdx.x;
  float lambda = expf(lam[0]) + 0.05f;
  int gq = i >> 7;
  int rb = gq >> 12;
  int q = gq & 4095;
  int dv = i & 127;
  int b = b0 + rb;
  float inv1 = 1.f / ls[(size_t)b * SEQ + q];
  float inv2 = lambda / ls[NTOK + (size_t)b * SEQ + q];
  size_t ai = (size_t)(rb * 2) * (SEQ * 128) + (size_t)q * 128 + dv;
  float4 a = ((const float4*)O12)[ai];
  float4 c = ((const float4*)O12)[ai + SEQ * 128];
  float4 r;
  r.x = a.x * inv1 - c.x * inv2;
  r.y = a.y * inv1 - c.y * inv2;
  r.z = a.z * inv1 - c.z * inv2;
  r.w = a.w * inv1 - c.w * inv2;
  ((float4*)out)[(size_t)(b * SEQ + q) * 128 + dv] = r;
}

// ---------------------------------------------------------------------------
extern "C" void kernel_launch(void* const* d_in, const int* in_sizes, int n_in,
                              void* d_out, int out_size, void* d_ws, size_t ws_size,
                              hipStream_t stream) {
  const float* X   = (const float*)d_in[0];
  const float* Wq  = (const float*)d_in[1];
  const float* bq  = (const float*)d_in[2];
  const float* Wk  = (const float*)d_in[3];
  const float* bk  = (const float*)d_in[4];
  const float* Wv  = (const float*)d_in[5];
  const float* bv  = (const float*)d_in[6];
  const float* lam = (const float*)d_in[7];
  float* out = (float*)d_out;

  char* ws = (char*)d_ws;
  size_t off = 0;
  auto alloc = [&](size_t b) { size_t r = off; off += (b + 255) & ~(size_t)255; return r; };
  unsigned short* Xb  = (unsigned short*)(ws + alloc((size_t)NTOK * EDIM * 2));    // 32 MiB
  unsigned short* Wb  = (unsigned short*)(ws + alloc((size_t)FQKV * EDIM * 2));    // 5 MiB
  float*          bc  = (float*)(ws + alloc((size_t)FQKV * 4));
  unsigned short* QK  = (unsigned short*)(ws + alloc((size_t)NTOK * FQK * 2));     // 64 MiB
  unsigned short* Vt  = (unsigned short*)(ws + alloc((size_t)NB * DHEAD * SEQ * 2)); // 16 MiB
  unsigned short* E_c = (unsigned short*)(ws + alloc((size_t)4 * SEQ * SEQ * 2));  // 128 MiB
  float*          ls  = (float*)(ws + alloc((size_t)2 * NTOK * 4));                // 128 KiB
  float* O12 = (float*)Xb;  // 32 MiB alias; Xb dead after k_v
  // total ws ~245.2 MiB (< 256 MiB)

  k_cvt_x<<<dim3((NTOK * EDIM / 4) / 256), dim3(256), 0, stream>>>(X, Xb);
  k_pack_w<<<dim3((FQKV * EDIM / 4) / 256), dim3(256), 0, stream>>>(Wq, Wk, Wv, Wb);
  k_pack_b<<<dim3(10), dim3(256), 0, stream>>>(bq, bk, bv, bc);
  k_qk<<<dim3(FQK / 128, NTOK / 128), dim3(256), 0, stream>>>(Xb, Wb, bc, QK);
  k_v<<<dim3(SEQ / 128, DHEAD / 128, NB), dim3(256), 0, stream>>>(Xb, Wb, bc, Vt);
  k_zero_f<<<dim3(2 * NTOK / 256), dim3(256), 0, stream>>>(ls);
  for (int b0 = 0; b0 < NB; b0 += 2) {
    k_scores3<<<dim3(SEQ / 128, SEQ / 256, 4), dim3(512), 0, stream>>>(QK, E_c, ls, b0);
    k_pv4<<<dim3(512), dim3(256), 0, stream>>>(E_c, Vt, O12, b0);
    k_combine<<<dim3((2 * SEQ * DHEAD / 4) / 256), dim3(256), 0, stream>>>(O12, ls, lam, out, b0);
  }

  (void)in_sizes; (void)n_in; (void)out_size; (void)ws_size;
}